// Round 1
// baseline (287.410 us; speedup 1.0000x reference)
//
#include <hip/hip_runtime.h>

typedef unsigned short u16;
typedef unsigned int u32;
typedef float f32x4 __attribute__((ext_vector_type(4)));
typedef __bf16 bf16x8 __attribute__((ext_vector_type(8)));
typedef u16 u16x4v __attribute__((ext_vector_type(4)));

#define NHEAD 12
#define NN 2048
#define CC 768

#define GLOBAL_AS __attribute__((address_space(1)))
#define LDS_AS __attribute__((address_space(3)))

__device__ __forceinline__ u16 f2bf(float f) {
  u32 u = __builtin_bit_cast(u32, f);
  u += 0x7fffu + ((u >> 16) & 1u);
  return (u16)(u >> 16);
}
__device__ __forceinline__ float bf2f(u16 h) {
  u32 u = ((u32)h) << 16;
  return __builtin_bit_cast(float, u);
}

// ---------------- fp32 -> bf16 convert ----------------
__global__ __launch_bounds__(256) void cvt_kernel(const float* __restrict__ in,
                                                  u16* __restrict__ out, int n4) {
  int i = blockIdx.x * 256 + threadIdx.x;
  if (i < n4) {
    float4 v = ((const float4*)in)[i];
    u16x4v o = {f2bf(v.x), f2bf(v.y), f2bf(v.z), f2bf(v.w)};
    ((u16x4v*)out)[i] = o;
  }
}

// ---------------- LayerNorm: f32 in -> bf16 out (wave per row) ----------------
__global__ __launch_bounds__(256) void ln_kernel(const float* __restrict__ x,
                                                 const float* __restrict__ gw,
                                                 const float* __restrict__ bw,
                                                 u16* __restrict__ out) {
  int row = blockIdx.x * 4 + (threadIdx.x >> 6);
  int lane = threadIdx.x & 63;
  const float* xr = x + (size_t)row * CC + lane * 12;
  float v[12];
  *(float4*)&v[0] = *(const float4*)(xr + 0);
  *(float4*)&v[4] = *(const float4*)(xr + 4);
  *(float4*)&v[8] = *(const float4*)(xr + 8);
  float s = 0.f, sq = 0.f;
#pragma unroll
  for (int j = 0; j < 12; ++j) { s += v[j]; sq += v[j] * v[j]; }
#pragma unroll
  for (int o = 1; o < 64; o <<= 1) { s += __shfl_xor(s, o); sq += __shfl_xor(sq, o); }
  float mean = s * (1.f / CC);
  float var = sq * (1.f / CC) - mean * mean;
  float rs = rsqrtf(var + 1e-5f);
  u16 ob[12];
#pragma unroll
  for (int j = 0; j < 12; ++j) {
    int c = lane * 12 + j;
    ob[j] = f2bf((v[j] - mean) * rs * gw[c] + bw[c]);
  }
  u32* orow = (u32*)(out + (size_t)row * CC + lane * 12);
#pragma unroll
  for (int j = 0; j < 6; ++j) orow[j] = (u32)ob[2 * j] | ((u32)ob[2 * j + 1] << 16);
}

// ---------------- bf16 MFMA GEMM: C[M,N] = A[M,K] @ Bw[N,K]^T ----------------
// 128x128 tile, BK=64, 4 waves (2x2), XOR-swizzled LDS with pre-swizzled
// global_load_lds source (both-sides swizzle, guide §5.5 T2 / rule 21).
template <int OB, int HASB, int ACT, int RES>
__global__ __launch_bounds__(256) void gemm_kernel(
    const u16* __restrict__ A, const u16* __restrict__ Bw,
    const float* __restrict__ bias, const float* __restrict__ res,
    void* __restrict__ Cout, int M, int N, int K) {
  __shared__ __align__(16) u16 Alds[128 * 64];
  __shared__ __align__(16) u16 Blds[128 * 64];
  const int tid = threadIdx.x;
  const int lane = tid & 63, wave = tid >> 6;
  const int l15 = lane & 15, g = lane >> 4;
  const int bm = blockIdx.x * 128, bn = blockIdx.y * 128;
  const int wm = (wave >> 1) * 64, wn = (wave & 1) * 64;
  f32x4 acc[4][4] = {};

  for (int kt = 0; kt < K; kt += 64) {
#pragma unroll
    for (int i = 0; i < 4; ++i) {
      int ob = i * 4096 + wave * 1024;  // wave-uniform LDS byte base
      int lb = ob + lane * 16;          // this lane's linear tile byte
      int row = lb >> 7;
      int cb = (lb & 127) ^ ((row & 7) << 4);  // pre-swizzled source column
      const u16* sa = A + (size_t)(bm + row) * K + kt + (cb >> 1);
      const u16* sb = Bw + (size_t)(bn + row) * K + kt + (cb >> 1);
      __builtin_amdgcn_global_load_lds((const GLOBAL_AS void*)sa,
                                       (LDS_AS void*)(Alds + (ob >> 1)), 16, 0, 0);
      __builtin_amdgcn_global_load_lds((const GLOBAL_AS void*)sb,
                                       (LDS_AS void*)(Blds + (ob >> 1)), 16, 0, 0);
    }
    __syncthreads();
#pragma unroll
    for (int ks = 0; ks < 2; ++ks) {
      bf16x8 af[4], bfr[4];
#pragma unroll
      for (int mi = 0; mi < 4; ++mi) {
        int row = wm + mi * 16 + l15;
        int cb = (ks * 64 + g * 16) ^ ((row & 7) << 4);
        af[mi] = *(const bf16x8*)&Alds[row * 64 + (cb >> 1)];
      }
#pragma unroll
      for (int ni = 0; ni < 4; ++ni) {
        int row = wn + ni * 16 + l15;
        int cb = (ks * 64 + g * 16) ^ ((row & 7) << 4);
        bfr[ni] = *(const bf16x8*)&Blds[row * 64 + (cb >> 1)];
      }
#pragma unroll
      for (int mi = 0; mi < 4; ++mi)
#pragma unroll
        for (int ni = 0; ni < 4; ++ni)
          acc[mi][ni] = __builtin_amdgcn_mfma_f32_16x16x32_bf16(af[mi], bfr[ni],
                                                                acc[mi][ni], 0, 0, 0);
    }
    __syncthreads();
  }
  // epilogue: D layout col = lane&15, row = (lane>>4)*4 + r
#pragma unroll
  for (int mi = 0; mi < 4; ++mi) {
#pragma unroll
    for (int ni = 0; ni < 4; ++ni) {
      int col = bn + wn + ni * 16 + l15;
      float bs = HASB ? bias[col] : 0.f;
#pragma unroll
      for (int r = 0; r < 4; ++r) {
        int rowm = bm + wm + mi * 16 + g * 4 + r;
        float v = acc[mi][ni][r] + bs;
        if (ACT) v = 0.5f * v * (1.f + erff(v * 0.70710678118654752f));
        if (RES) v += res[(size_t)rowm * N + col];
        if (OB)
          ((u16*)Cout)[(size_t)rowm * N + col] = f2bf(v);
        else
          ((float*)Cout)[(size_t)rowm * N + col] = v;
      }
    }
  }
}

// ---------------- Vsum: vs[q4][bh][d] = sum over 512 keys of V ----------------
__global__ __launch_bounds__(256) void vsum_kernel(const u16* __restrict__ qkv,
                                                   float* __restrict__ vs) {
  int bh = blockIdx.x, q4 = blockIdx.y;
  int b = bh / NHEAD, h = bh % NHEAD;
  int d = threadIdx.x & 63, part = threadIdx.x >> 6;
  float s = 0.f;
  for (int n = q4 * 512 + part; n < q4 * 512 + 512; n += 4)
    s += bf2f(qkv[(size_t)(b * NN + n) * 2304 + 2 * CC + h * 64 + d]);
  __shared__ float red[256];
  red[threadIdx.x] = s;
  __syncthreads();
  if (threadIdx.x < 64) {
    float t = red[threadIdx.x] + red[threadIdx.x + 64] + red[threadIdx.x + 128] +
              red[threadIdx.x + 192];
    vs[q4 * (24 * 64) + bh * 64 + threadIdx.x] = t;
  }
}

// ---------------- Flash attention with policy mask ----------------
// Per block: one (b,h), 64 q rows; wave w owns 16 q rows. Swapped QK^T
// (mfma(K,Q)) so softmax reduce = in-lane over 16 vals + shfl_xor(16,32).
__global__ __launch_bounds__(256) void attn_kernel(const u16* __restrict__ qkv,
                                                   const float* __restrict__ policy,
                                                   const float* __restrict__ vsum,
                                                   u16* __restrict__ o) {
  __shared__ __align__(16) u16 Klds[64 * 64];   // [key][d], XOR-swizzled
  __shared__ __align__(16) u16 Vlds[64 * 64];   // V^T [d][key], XOR-swizzled
  __shared__ __align__(16) u16 Plds[4][16 * 64];// per-wave P [q][key], swizzled
  const int bh = blockIdx.y, b = bh / NHEAD, h = bh % NHEAD;
  const int qtile = blockIdx.x * 64;
  const int tid = threadIdx.x, lane = tid & 63, w = tid >> 6;
  const int l15 = lane & 15, g = lane >> 4;
  const int qbase = qtile + w * 16;

  bf16x8 qf0, qf1;  // B-operand layout: Q[q=l15][d = g*8+j (+32)]
  {
    const u16* qp = qkv + (size_t)(b * NN + qbase + l15) * 2304 + h * 64 + g * 8;
    qf0 = *(const bf16x8*)qp;
    qf1 = *(const bf16x8*)(qp + 32);
  }
  float m_cur = -3.0e38f, l_run = 0.f;
  f32x4 acc_o[4] = {};
  const int skey = tid >> 2, part = tid & 3;

  for (int kv = 0; kv < NN; kv += 64) {
    // ---- stage K (swizzled rows) and V^T (transposed, swizzled) ----
    {
      const u16* kr = qkv + (size_t)(b * NN + kv + skey) * 2304 + CC + h * 64 + part * 16;
      uint4 k0 = *(const uint4*)kr;
      uint4 k1 = *(const uint4*)(kr + 8);
      int c0 = (part * 32) ^ ((skey & 7) << 4);
      int c1 = (part * 32 + 16) ^ ((skey & 7) << 4);
      *(uint4*)&Klds[skey * 64 + (c0 >> 1)] = k0;
      *(uint4*)&Klds[skey * 64 + (c1 >> 1)] = k1;
      const u16* vr = qkv + (size_t)(b * NN + kv + skey) * 2304 + 2 * CC + h * 64 + part * 16;
      uint4 v0 = *(const uint4*)vr;
      uint4 v1 = *(const uint4*)(vr + 8);
      u32 vw[8] = {v0.x, v0.y, v0.z, v0.w, v1.x, v1.y, v1.z, v1.w};
#pragma unroll
      for (int j = 0; j < 16; ++j) {
        u16 val = (u16)(vw[j >> 1] >> ((j & 1) * 16));
        int d = part * 16 + j;
        int byte_ = (d * 128 + skey * 2) ^ ((d & 7) << 4);
        Vlds[byte_ >> 1] = val;
      }
    }
    __syncthreads();
    // ---- S^T fragments: mfma(K, Q); lane holds S[key=kf*16+g*4+r][q=l15] ----
    float sv[16];
#pragma unroll
    for (int kf = 0; kf < 4; ++kf) {
      int row = kf * 16 + l15;
      int c0 = (g * 16) ^ ((row & 7) << 4);
      int c1 = (64 + g * 16) ^ ((row & 7) << 4);
      bf16x8 k0 = *(const bf16x8*)&Klds[row * 64 + (c0 >> 1)];
      bf16x8 k1 = *(const bf16x8*)&Klds[row * 64 + (c1 >> 1)];
      f32x4 t = {};
      t = __builtin_amdgcn_mfma_f32_16x16x32_bf16(k0, qf0, t, 0, 0, 0);
      t = __builtin_amdgcn_mfma_f32_16x16x32_bf16(k1, qf1, t, 0, 0, 0);
#pragma unroll
      for (int r = 0; r < 4; ++r) sv[kf * 4 + r] = t[r] * 0.125f;  // * HD^-0.5
    }
    // ---- online softmax (max over raw scores, mask applied post-exp) ----
    float tmax = sv[0];
#pragma unroll
    for (int j = 1; j < 16; ++j) tmax = fmaxf(tmax, sv[j]);
    tmax = fmaxf(tmax, __shfl_xor(tmax, 16));
    tmax = fmaxf(tmax, __shfl_xor(tmax, 32));
    float m_new = fmaxf(m_cur, tmax);
    float alpha = __expf(m_cur - m_new);
    int qglob = qbase + l15;
    float psum = 0.f;
    u16 pb[16];
#pragma unroll
    for (int kf = 0; kf < 4; ++kf) {
#pragma unroll
      for (int r = 0; r < 4; ++r) {
        int key = kv + kf * 16 + g * 4 + r;
        float ap = policy[b * NN + key];
        ap = (key == qglob) ? 1.f : ap;  // always attend to self
        float e = __expf(sv[kf * 4 + r] - m_new) * ap;
        psum += e;
        pb[kf * 4 + r] = f2bf(e);
      }
    }
    psum += __shfl_xor(psum, 16);
    psum += __shfl_xor(psum, 32);
    l_run = l_run * alpha + psum;
    m_cur = m_new;
    // ---- P -> per-wave LDS (q-major, swizzled), packed 4 keys ----
#pragma unroll
    for (int kf = 0; kf < 4; ++kf) {
      int cb = (kf * 32 + g * 8) ^ ((l15 & 7) << 4);
      u16x4v pk = {pb[kf * 4 + 0], pb[kf * 4 + 1], pb[kf * 4 + 2], pb[kf * 4 + 3]};
      *(u16x4v*)&Plds[w][l15 * 64 + (cb >> 1)] = pk;
    }
    // ---- rescale O accumulator (rows q = g*4+r need alpha from lane q) ----
    float ar0 = __shfl(alpha, g * 4 + 0);
    float ar1 = __shfl(alpha, g * 4 + 1);
    float ar2 = __shfl(alpha, g * 4 + 2);
    float ar3 = __shfl(alpha, g * 4 + 3);
#pragma unroll
    for (int df = 0; df < 4; ++df) {
      acc_o[df][0] *= ar0; acc_o[df][1] *= ar1;
      acc_o[df][2] *= ar2; acc_o[df][3] *= ar3;
    }
    // ---- PV: A = P[q][k] from Plds, B = V[k][d] from Vlds(=V^T rows) ----
#pragma unroll
    for (int ks = 0; ks < 2; ++ks) {
      int cbp = (ks * 64 + g * 16) ^ ((l15 & 7) << 4);
      bf16x8 pf = *(const bf16x8*)&Plds[w][l15 * 64 + (cbp >> 1)];
#pragma unroll
      for (int df = 0; df < 4; ++df) {
        int drow = df * 16 + l15;
        int cbv = (ks * 64 + g * 16) ^ ((drow & 7) << 4);
        bf16x8 vf = *(const bf16x8*)&Vlds[drow * 64 + (cbv >> 1)];
        acc_o[df] = __builtin_amdgcn_mfma_f32_16x16x32_bf16(pf, vf, acc_o[df], 0, 0, 0);
      }
    }
    __syncthreads();
  }
  // ---- epilogue: O = (acc + (eps/n)*Vsum) / (l + eps) ----
  float lr[4];
#pragma unroll
  for (int r = 0; r < 4; ++r) lr[r] = __shfl(l_run, g * 4 + r);
  const float epsn = 1e-6f / (float)NN;
#pragma unroll
  for (int df = 0; df < 4; ++df) {
    int d = df * 16 + l15;
    float vsv = vsum[bh * 64 + d] + vsum[1536 + bh * 64 + d] +
                vsum[2 * 1536 + bh * 64 + d] + vsum[3 * 1536 + bh * 64 + d];
#pragma unroll
    for (int r = 0; r < 4; ++r) {
      float ov = (acc_o[df][r] + epsn * vsv) / (lr[r] + 1e-6f);
      int qg = qbase + g * 4 + r;
      o[(size_t)(b * NN + qg) * CC + h * 64 + d] = f2bf(ov);
    }
  }
}

extern "C" void kernel_launch(void* const* d_in, const int* in_sizes, int n_in,
                              void* d_out, int out_size, void* d_ws, size_t ws_size,
                              hipStream_t stream) {
  const float* x = (const float*)d_in[0];
  const float* policy = (const float*)d_in[1];
  const float* ln1g = (const float*)d_in[2];
  const float* ln1b = (const float*)d_in[3];
  const float* qkvw = (const float*)d_in[4];
  const float* projw = (const float*)d_in[5];
  const float* projb = (const float*)d_in[6];
  const float* ln2g = (const float*)d_in[7];
  const float* ln2b = (const float*)d_in[8];
  const float* fc1w = (const float*)d_in[9];
  const float* fc1b = (const float*)d_in[10];
  const float* fc2w = (const float*)d_in[11];
  const float* fc2b = (const float*)d_in[12];
  float* out = (float*)d_out;

  char* ws = (char*)d_ws;
  size_t off = 0;
  auto alloc = [&](size_t bytes) {
    void* p = ws + off;
    off = (off + bytes + 255) & ~(size_t)255;
    return p;
  };
  u16* wq = (u16*)alloc((size_t)2304 * 768 * 2);
  u16* wp = (u16*)alloc((size_t)768 * 768 * 2);
  u16* w1 = (u16*)alloc((size_t)3072 * 768 * 2);
  u16* w2 = (u16*)alloc((size_t)768 * 3072 * 2);
  u16* hbuf = (u16*)alloc((size_t)4096 * 768 * 2);
  u16* qkv = (u16*)alloc((size_t)4096 * 2304 * 2);  // region C (reused as f1)
  u16* obuf = (u16*)alloc((size_t)4096 * 768 * 2);  // contiguous after qkv
  float* x1 = (float*)alloc((size_t)4096 * 768 * 4);
  float* vs = (float*)alloc((size_t)4 * 24 * 64 * 4);
  u16* f1 = qkv;  // 4096*3072*2 = qkv(18.9MB)+obuf(6.3MB) region, both dead by then

  cvt_kernel<<<1728, 256, 0, stream>>>(qkvw, wq, 442368);
  cvt_kernel<<<576, 256, 0, stream>>>(projw, wp, 147456);
  cvt_kernel<<<2304, 256, 0, stream>>>(fc1w, w1, 589824);
  cvt_kernel<<<2304, 256, 0, stream>>>(fc2w, w2, 589824);

  ln_kernel<<<1024, 256, 0, stream>>>(x, ln1g, ln1b, hbuf);
  gemm_kernel<1, 0, 0, 0><<<dim3(32, 18), 256, 0, stream>>>(
      hbuf, wq, nullptr, nullptr, qkv, 4096, 2304, 768);
  vsum_kernel<<<dim3(24, 4), 256, 0, stream>>>(qkv, vs);
  attn_kernel<<<dim3(32, 24), 256, 0, stream>>>(qkv, policy, vs, obuf);
  gemm_kernel<0, 1, 0, 1><<<dim3(32, 6), 256, 0, stream>>>(
      obuf, wp, projb, x, x1, 4096, 768, 768);
  ln_kernel<<<1024, 256, 0, stream>>>(x1, ln2g, ln2b, hbuf);
  gemm_kernel<1, 1, 1, 0><<<dim3(32, 24), 256, 0, stream>>>(
      hbuf, w1, fc1b, nullptr, f1, 4096, 3072, 768);
  gemm_kernel<0, 1, 0, 1><<<dim3(32, 6), 256, 0, stream>>>(
      f1, w2, fc2b, x1, out, 4096, 768, 3072);
}

// Round 2
// 252.647 us; speedup vs baseline: 1.1376x; 1.1376x over previous
//
#include <hip/hip_runtime.h>

typedef unsigned short u16;
typedef unsigned int u32;
typedef float f32x4 __attribute__((ext_vector_type(4)));
typedef __bf16 bf16x8 __attribute__((ext_vector_type(8)));
typedef __bf16 bf16x4v __attribute__((ext_vector_type(4)));
typedef u16 u16x4v __attribute__((ext_vector_type(4)));
typedef u32 u32x2 __attribute__((ext_vector_type(2)));
typedef u32 u32x4 __attribute__((ext_vector_type(4)));

#define NHEAD 12
#define NN 2048
#define CC 768

#define GLOBAL_AS __attribute__((address_space(1)))
#define LDS_AS __attribute__((address_space(3)))

__device__ __forceinline__ u16 tobf(float f) {
  __bf16 h = (__bf16)f;
  return __builtin_bit_cast(u16, h);
}
__device__ __forceinline__ float bf2f(u16 h) {
  u32 u = ((u32)h) << 16;
  return __builtin_bit_cast(float, u);
}

// ---------------- fused fp32 -> bf16 convert of all 4 weights ----------------
#define N4_QKV 442368
#define N4_PROJ 147456
#define N4_FC 589824
__global__ __launch_bounds__(256) void cvt4_kernel(
    const float* __restrict__ a, const float* __restrict__ b,
    const float* __restrict__ c, const float* __restrict__ d,
    u16* __restrict__ oa, u16* __restrict__ ob, u16* __restrict__ oc,
    u16* __restrict__ od) {
  int i = blockIdx.x * 256 + threadIdx.x;
  const float* src;
  u16* dst;
  if (i < N4_QKV) {
    src = a; dst = oa;
  } else if (i < N4_QKV + N4_PROJ) {
    i -= N4_QKV; src = b; dst = ob;
  } else if (i < N4_QKV + N4_PROJ + N4_FC) {
    i -= N4_QKV + N4_PROJ; src = c; dst = oc;
  } else {
    i -= N4_QKV + N4_PROJ + N4_FC; src = d; dst = od;
    if (i >= N4_FC) return;
  }
  float4 v = ((const float4*)src)[i];
  u16x4v o = {tobf(v.x), tobf(v.y), tobf(v.z), tobf(v.w)};
  ((u16x4v*)dst)[i] = o;
}

// ---------------- LayerNorm: f32 in -> bf16 out (wave per row) ----------------
__global__ __launch_bounds__(256) void ln_kernel(const float* __restrict__ x,
                                                 const float* __restrict__ gw,
                                                 const float* __restrict__ bw,
                                                 u16* __restrict__ out) {
  int row = blockIdx.x * 4 + (threadIdx.x >> 6);
  int lane = threadIdx.x & 63;
  const float* xr = x + (size_t)row * CC + lane * 12;
  float v[12];
  *(float4*)&v[0] = *(const float4*)(xr + 0);
  *(float4*)&v[4] = *(const float4*)(xr + 4);
  *(float4*)&v[8] = *(const float4*)(xr + 8);
  float s = 0.f, sq = 0.f;
#pragma unroll
  for (int j = 0; j < 12; ++j) { s += v[j]; sq += v[j] * v[j]; }
#pragma unroll
  for (int o = 1; o < 64; o <<= 1) { s += __shfl_xor(s, o); sq += __shfl_xor(sq, o); }
  float mean = s * (1.f / CC);
  float var = sq * (1.f / CC) - mean * mean;
  float rs = rsqrtf(var + 1e-5f);
  u16 ob[12];
#pragma unroll
  for (int j = 0; j < 12; ++j) {
    int c = lane * 12 + j;
    ob[j] = tobf((v[j] - mean) * rs * gw[c] + bw[c]);
  }
  u32* orow = (u32*)(out + (size_t)row * CC + lane * 12);
#pragma unroll
  for (int j = 0; j < 6; ++j) orow[j] = (u32)ob[2 * j] | ((u32)ob[2 * j + 1] << 16);
}

// ---------------- bf16 MFMA GEMM: C[M,N] = A[M,K] @ Bw[N,K]^T ----------------
// BMx128 tile, BK=64, 4 waves, XOR-swizzled LDS with pre-swizzled
// global_load_lds source (both-sides swizzle).
template <int BM, int OB, int HASB, int ACT, int RES>
__global__ __launch_bounds__(256) void gemm_kernel(
    const u16* __restrict__ A, const u16* __restrict__ Bw,
    const float* __restrict__ bias, const float* __restrict__ res,
    void* __restrict__ Cout, int M, int N, int K) {
  constexpr int MW = BM / 2;   // per-wave M extent
  constexpr int MF = MW / 16;  // per-wave m fragments
  __shared__ __align__(16) u16 Alds[BM * 64];
  __shared__ __align__(16) u16 Blds[128 * 64];
  const int tid = threadIdx.x;
  const int lane = tid & 63, wave = tid >> 6;
  const int l15 = lane & 15, g = lane >> 4;
  const int bm = blockIdx.x * BM, bn = blockIdx.y * 128;
  const int wm = (wave >> 1) * MW, wn = (wave & 1) * 64;
  f32x4 acc[MF][4] = {};

  for (int kt = 0; kt < K; kt += 64) {
#pragma unroll
    for (int i = 0; i < BM / 32; ++i) {
      int ob_ = i * 4096 + wave * 1024;
      int lb = ob_ + lane * 16;
      int row = lb >> 7;
      int cb = (lb & 127) ^ ((row & 7) << 4);
      const u16* sa = A + (size_t)(bm + row) * K + kt + (cb >> 1);
      __builtin_amdgcn_global_load_lds((const GLOBAL_AS void*)sa,
                                       (LDS_AS void*)(Alds + (ob_ >> 1)), 16, 0, 0);
    }
#pragma unroll
    for (int i = 0; i < 4; ++i) {
      int ob_ = i * 4096 + wave * 1024;
      int lb = ob_ + lane * 16;
      int row = lb >> 7;
      int cb = (lb & 127) ^ ((row & 7) << 4);
      const u16* sb = Bw + (size_t)(bn + row) * K + kt + (cb >> 1);
      __builtin_amdgcn_global_load_lds((const GLOBAL_AS void*)sb,
                                       (LDS_AS void*)(Blds + (ob_ >> 1)), 16, 0, 0);
    }
    __syncthreads();
#pragma unroll
    for (int ks = 0; ks < 2; ++ks) {
      bf16x8 af[MF], bfr[4];
#pragma unroll
      for (int mi = 0; mi < MF; ++mi) {
        int row = wm + mi * 16 + l15;
        int cb = (ks * 64 + g * 16) ^ ((row & 7) << 4);
        af[mi] = *(const bf16x8*)&Alds[row * 64 + (cb >> 1)];
      }
#pragma unroll
      for (int ni = 0; ni < 4; ++ni) {
        int row = wn + ni * 16 + l15;
        int cb = (ks * 64 + g * 16) ^ ((row & 7) << 4);
        bfr[ni] = *(const bf16x8*)&Blds[row * 64 + (cb >> 1)];
      }
#pragma unroll
      for (int mi = 0; mi < MF; ++mi)
#pragma unroll
        for (int ni = 0; ni < 4; ++ni)
          acc[mi][ni] = __builtin_amdgcn_mfma_f32_16x16x32_bf16(af[mi], bfr[ni],
                                                                acc[mi][ni], 0, 0, 0);
    }
    __syncthreads();
  }
#pragma unroll
  for (int mi = 0; mi < MF; ++mi) {
#pragma unroll
    for (int ni = 0; ni < 4; ++ni) {
      int col = bn + wn + ni * 16 + l15;
      float bs = HASB ? bias[col] : 0.f;
#pragma unroll
      for (int r = 0; r < 4; ++r) {
        int rowm = bm + wm + mi * 16 + g * 4 + r;
        float v = acc[mi][ni][r] + bs;
        if (ACT) v = 0.5f * v * (1.f + erff(v * 0.70710678118654752f));
        if (RES) v += res[(size_t)rowm * N + col];
        if (OB)
          ((u16*)Cout)[(size_t)rowm * N + col] = tobf(v);
        else
          ((float*)Cout)[(size_t)rowm * N + col] = v;
      }
    }
  }
}

// ---------------- Vsum: vs[q4][bh][d] = partial sums of V ----------------
__global__ __launch_bounds__(256) void vsum_kernel(const u16* __restrict__ qkv,
                                                   float* __restrict__ vs) {
  int bh = blockIdx.x, q4 = blockIdx.y;
  int b = bh / NHEAD, h = bh % NHEAD;
  int d = threadIdx.x & 63, part = threadIdx.x >> 6;
  float s = 0.f;
  for (int n = q4 * 512 + part; n < q4 * 512 + 512; n += 4)
    s += bf2f(qkv[(size_t)(b * NN + n) * 2304 + 2 * CC + h * 64 + d]);
  __shared__ float red[256];
  red[threadIdx.x] = s;
  __syncthreads();
  if (threadIdx.x < 64) {
    float t = red[threadIdx.x] + red[threadIdx.x + 64] + red[threadIdx.x + 128] +
              red[threadIdx.x + 192];
    vs[q4 * (24 * 64) + bh * 64 + threadIdx.x] = t;
  }
}

// ---------------- Flash attention with policy mask ----------------
// Double-buffered async K/V staging (global_load_lds), V in [kb][db][4][16]
// subtiled layout read via ds_read_b64_tr_b16, policy in LDS, log2-domain
// softmax with scale pre-folded into Q, defer-max with exact epilogue fixup.
#define SCL2E 0.18033688f  /* 0.125 * log2(e) */
__global__ __launch_bounds__(256) void attn_kernel(const u16* __restrict__ qkv,
                                                   const float* __restrict__ policy,
                                                   const float* __restrict__ vsum,
                                                   u16* __restrict__ o) {
  __shared__ __align__(16) u16 Klds[2][64 * 64];   // [key][d] XOR-swizzled rows
  __shared__ __align__(16) u16 Vlds[2][64 * 64];   // [kb][db][kr=4][dc=16] subtiled
  __shared__ __align__(16) u16 Plds[4][16 * 64];   // per-wave P, swizzled rows
  __shared__ float pol_lds[NN];
  const int bh = blockIdx.y, b = bh / NHEAD, h = bh % NHEAD;
  const int qtile = blockIdx.x * 64;
  const int tid = threadIdx.x, lane = tid & 63, w = tid >> 6;
  const int l15 = lane & 15, g = lane >> 4;
  const int qbase = qtile + w * 16;

  // ---- Q fragments, scale pre-folded (log2 domain) ----
  bf16x8 qf0, qf1;
  {
    const u16* qp = qkv + (size_t)(b * NN + qbase + l15) * 2304 + h * 64 + g * 8;
    bf16x8 r0 = *(const bf16x8*)qp;
    bf16x8 r1 = *(const bf16x8*)(qp + 32);
#pragma unroll
    for (int j = 0; j < 8; ++j) {
      qf0[j] = (__bf16)((float)r0[j] * SCL2E);
      qf1[j] = (__bf16)((float)r1[j] * SCL2E);
    }
  }

  // ---- per-lane staging sources (2 chunks per wave per array) ----
  const int I0 = w * 128 + lane, I1 = I0 + 64;
  const int kr0 = I0 >> 3, kc0 = (((I0 & 7) * 16) ^ ((kr0 & 7) << 4)) >> 1;
  const int kr1 = I1 >> 3, kc1 = (((I1 & 7) * 16) ^ ((kr1 & 7) << 4)) >> 1;
  const int vr0 = (I0 >> 5) * 4 + ((I0 & 7) >> 1), vc0 = ((I0 & 31) >> 3) * 16 + (I0 & 1) * 8;
  const int vr1 = (I1 >> 5) * 4 + ((I1 & 7) >> 1), vc1 = ((I1 & 31) >> 3) * 16 + (I1 & 1) * 8;
  const u16* pkA = qkv + (size_t)(b * NN + kr0) * 2304 + CC + h * 64 + kc0;
  const u16* pkB = qkv + (size_t)(b * NN + kr1) * 2304 + CC + h * 64 + kc1;
  const u16* pvA = qkv + (size_t)(b * NN + vr0) * 2304 + 2 * CC + h * 64 + vc0;
  const u16* pvB = qkv + (size_t)(b * NN + vr1) * 2304 + 2 * CC + h * 64 + vc1;
  const size_t adv = (size_t)64 * 2304;

  auto stage = [&](int buf) {
    __builtin_amdgcn_global_load_lds((const GLOBAL_AS void*)pkA,
                                     (LDS_AS void*)&Klds[buf][(w * 2 + 0) * 512], 16, 0, 0);
    __builtin_amdgcn_global_load_lds((const GLOBAL_AS void*)pkB,
                                     (LDS_AS void*)&Klds[buf][(w * 2 + 1) * 512], 16, 0, 0);
    __builtin_amdgcn_global_load_lds((const GLOBAL_AS void*)pvA,
                                     (LDS_AS void*)&Vlds[buf][(w * 2 + 0) * 512], 16, 0, 0);
    __builtin_amdgcn_global_load_lds((const GLOBAL_AS void*)pvB,
                                     (LDS_AS void*)&Vlds[buf][(w * 2 + 1) * 512], 16, 0, 0);
    pkA += adv; pkB += adv; pvA += adv; pvB += adv;
  };

  stage(0);
  {  // policy -> LDS
    float4 p0 = *(const float4*)&policy[b * NN + tid * 8];
    float4 p1 = *(const float4*)&policy[b * NN + tid * 8 + 4];
    *(float4*)&pol_lds[tid * 8] = p0;
    *(float4*)&pol_lds[tid * 8 + 4] = p1;
  }
  __syncthreads();

  float m_cur = -3.0e38f, m_true = -3.0e38f, l_run = 0.f;
  f32x4 acc_o[4] = {};
  const u32 vbase0 = (u32)(uintptr_t)(LDS_AS u16*)&Vlds[0][0] + (u32)(g * 1024 + l15 * 2);
  const int qglob = qbase + l15;

  for (int t = 0; t < 32; ++t) {
    const int cur = t & 1;
    const int kv = t * 64;
    if (t < 31) stage(cur ^ 1);

    // ---- QK^T (swapped): lane holds S[key=kf*16+g*4+r][q=l15] ----
    float sv[16];
#pragma unroll
    for (int kf = 0; kf < 4; ++kf) {
      int row = kf * 16 + l15;
      int sw = (row & 7) << 4;
      bf16x8 k0 = *(const bf16x8*)&Klds[cur][row * 64 + (((g * 16) ^ sw) >> 1)];
      bf16x8 k1 = *(const bf16x8*)&Klds[cur][row * 64 + (((64 + g * 16) ^ sw) >> 1)];
      f32x4 tacc = {};
      tacc = __builtin_amdgcn_mfma_f32_16x16x32_bf16(k0, qf0, tacc, 0, 0, 0);
      tacc = __builtin_amdgcn_mfma_f32_16x16x32_bf16(k1, qf1, tacc, 0, 0, 0);
#pragma unroll
      for (int r = 0; r < 4; ++r) sv[kf * 4 + r] = tacc[r];
    }
    // ---- online softmax in log2 domain, defer-max ----
    float tmax = sv[0];
#pragma unroll
    for (int j = 1; j < 16; ++j) tmax = fmaxf(tmax, sv[j]);
    tmax = fmaxf(tmax, __shfl_xor(tmax, 16));
    tmax = fmaxf(tmax, __shfl_xor(tmax, 32));
    m_true = fmaxf(m_true, tmax);
    const bool defer = __all(tmax <= m_cur + 8.f);
    const float m_new = defer ? m_cur : fmaxf(m_cur, tmax);
    float psum = 0.f;
    bf16x4v pbk[4];
#pragma unroll
    for (int kf = 0; kf < 4; ++kf) {
      float4 pol4 = *(const float4*)&pol_lds[kv + kf * 16 + g * 4];
#pragma unroll
      for (int r = 0; r < 4; ++r) {
        int key = kv + kf * 16 + g * 4 + r;
        float ap = (key == qglob) ? 1.f : ((const float*)&pol4)[r];
        float e = exp2f(sv[kf * 4 + r] - m_new) * ap;
        psum += e;
        pbk[kf][r] = (__bf16)e;
      }
    }
    psum += __shfl_xor(psum, 16);
    psum += __shfl_xor(psum, 32);
    if (!defer) {
      float alpha = exp2f(m_cur - m_new);
      l_run = l_run * alpha + psum;
      m_cur = m_new;
      float ar0 = __shfl(alpha, g * 4 + 0);
      float ar1 = __shfl(alpha, g * 4 + 1);
      float ar2 = __shfl(alpha, g * 4 + 2);
      float ar3 = __shfl(alpha, g * 4 + 3);
#pragma unroll
      for (int df = 0; df < 4; ++df) {
        acc_o[df][0] *= ar0; acc_o[df][1] *= ar1;
        acc_o[df][2] *= ar2; acc_o[df][3] *= ar3;
      }
    } else {
      l_run += psum;
    }
    // ---- P -> per-wave LDS (swizzled rows) ----
#pragma unroll
    for (int kf = 0; kf < 4; ++kf) {
      int cb = (kf * 32 + g * 8) ^ ((l15 & 7) << 4);
      *(bf16x4v*)&Plds[w][l15 * 64 + (cb >> 1)] = pbk[kf];
    }
    // ---- V fragments via hardware transpose read ----
    u32x2 tr[2][4][2];
    const u32 vab = vbase0 + (u32)(cur * 8192);
#pragma unroll
    for (int ks = 0; ks < 2; ++ks)
#pragma unroll
      for (int df = 0; df < 4; ++df) {
        u32 va = vab + ks * 4096 + df * 128;
        asm volatile("ds_read_b64_tr_b16 %0, %1 offset:0" : "=v"(tr[ks][df][0]) : "v"(va));
        asm volatile("ds_read_b64_tr_b16 %0, %1 offset:512" : "=v"(tr[ks][df][1]) : "v"(va));
      }
    asm volatile("s_waitcnt lgkmcnt(0)" ::: "memory");
    __builtin_amdgcn_sched_barrier(0);
    // ---- PV ----
#pragma unroll
    for (int ks = 0; ks < 2; ++ks) {
      int cbp = (ks * 64 + g * 16) ^ ((l15 & 7) << 4);
      bf16x8 pf = *(const bf16x8*)&Plds[w][l15 * 64 + (cbp >> 1)];
#pragma unroll
      for (int df = 0; df < 4; ++df) {
        u32x4 tmp = {tr[ks][df][0].x, tr[ks][df][0].y, tr[ks][df][1].x, tr[ks][df][1].y};
        bf16x8 vf = __builtin_bit_cast(bf16x8, tmp);
        acc_o[df] = __builtin_amdgcn_mfma_f32_16x16x32_bf16(pf, vf, acc_o[df], 0, 0, 0);
      }
    }
    __syncthreads();
  }
  // ---- epilogue: rescale deferred max to true max, add eps terms ----
  float s_adj = exp2f(m_cur - m_true);
  float lr[4], sr[4];
#pragma unroll
  for (int r = 0; r < 4; ++r) {
    lr[r] = __shfl(l_run, g * 4 + r);
    sr[r] = __shfl(s_adj, g * 4 + r);
  }
  const float epsn = 1e-6f / (float)NN;
#pragma unroll
  for (int df = 0; df < 4; ++df) {
    int d = df * 16 + l15;
    float vsv = vsum[bh * 64 + d] + vsum[1536 + bh * 64 + d] +
                vsum[2 * 1536 + bh * 64 + d] + vsum[3 * 1536 + bh * 64 + d];
#pragma unroll
    for (int r = 0; r < 4; ++r) {
      float ov = (acc_o[df][r] * sr[r] + epsn * vsv) / (lr[r] * sr[r] + 1e-6f);
      int qg = qbase + g * 4 + r;
      o[(size_t)(b * NN + qg) * CC + h * 64 + d] = tobf(ov);
    }
  }
}

extern "C" void kernel_launch(void* const* d_in, const int* in_sizes, int n_in,
                              void* d_out, int out_size, void* d_ws, size_t ws_size,
                              hipStream_t stream) {
  const float* x = (const float*)d_in[0];
  const float* policy = (const float*)d_in[1];
  const float* ln1g = (const float*)d_in[2];
  const float* ln1b = (const float*)d_in[3];
  const float* qkvw = (const float*)d_in[4];
  const float* projw = (const float*)d_in[5];
  const float* projb = (const float*)d_in[6];
  const float* ln2g = (const float*)d_in[7];
  const float* ln2b = (const float*)d_in[8];
  const float* fc1w = (const float*)d_in[9];
  const float* fc1b = (const float*)d_in[10];
  const float* fc2w = (const float*)d_in[11];
  const float* fc2b = (const float*)d_in[12];
  float* out = (float*)d_out;

  char* ws = (char*)d_ws;
  size_t off = 0;
  auto alloc = [&](size_t bytes) {
    void* p = ws + off;
    off = (off + bytes + 255) & ~(size_t)255;
    return p;
  };
  u16* wq = (u16*)alloc((size_t)2304 * 768 * 2);
  u16* wp = (u16*)alloc((size_t)768 * 768 * 2);
  u16* w1 = (u16*)alloc((size_t)3072 * 768 * 2);
  u16* w2 = (u16*)alloc((size_t)768 * 3072 * 2);
  u16* hbuf = (u16*)alloc((size_t)4096 * 768 * 2);
  u16* qkv = (u16*)alloc((size_t)4096 * 2304 * 2);  // reused as f1
  u16* obuf = (u16*)alloc((size_t)4096 * 768 * 2);  // contiguous after qkv
  float* x1 = (float*)alloc((size_t)4096 * 768 * 4);
  float* vs = (float*)alloc((size_t)4 * 24 * 64 * 4);
  u16* f1 = qkv;  // qkv+obuf region dead by FC1 time

  cvt4_kernel<<<6912, 256, 0, stream>>>(qkvw, projw, fc1w, fc2w, wq, wp, w1, w2);

  ln_kernel<<<1024, 256, 0, stream>>>(x, ln1g, ln1b, hbuf);
  gemm_kernel<128, 1, 0, 0, 0><<<dim3(32, 18), 256, 0, stream>>>(
      hbuf, wq, nullptr, nullptr, qkv, 4096, 2304, 768);
  vsum_kernel<<<dim3(24, 4), 256, 0, stream>>>(qkv, vs);
  attn_kernel<<<dim3(32, 24), 256, 0, stream>>>(qkv, policy, vs, obuf);
  gemm_kernel<64, 0, 1, 0, 1><<<dim3(64, 6), 256, 0, stream>>>(
      obuf, wp, projb, x, x1, 4096, 768, 768);
  ln_kernel<<<1024, 256, 0, stream>>>(x1, ln2g, ln2b, hbuf);
  gemm_kernel<128, 1, 1, 1, 0><<<dim3(32, 24), 256, 0, stream>>>(
      hbuf, w1, fc1b, nullptr, f1, 4096, 3072, 768);
  gemm_kernel<64, 0, 1, 0, 1><<<dim3(64, 6), 256, 0, stream>>>(
      f1, w2, fc2b, x1, out, 4096, 768, 3072);
}